// Round 1
// baseline (1219.316 us; speedup 1.0000x reference)
//
#include <hip/hip_runtime.h>
#include <hip/hip_bf16.h>
#include <stdint.h>

// 3D scalar HMM forward. Constants from the reference:
#define XY 32
#define ZS 16
#define NST 16384          // N = XY*XY*ZS
#define NMASK 16383        // N is pow2 -> mod == AND
#define VOC 10000
#define BB 32
#define TT 64
#define LL 16

#define LOG2E 1.4426950408889634f
#define LN2F  0.6931471805599453f

__device__ __forceinline__ float fexp2(float x) {
#if __has_builtin(__builtin_amdgcn_exp2f)
  return __builtin_amdgcn_exp2f(x);
#else
  return exp2f(x);
#endif
}
__device__ __forceinline__ float flog2(float x) {
#if __has_builtin(__builtin_amdgcn_logf)
  return __builtin_amdgcn_logf(x);
#else
  return log2f(x);
#endif
}

__device__ __forceinline__ float waveMax(float v) {
  #pragma unroll
  for (int o = 32; o >= 1; o >>= 1) v = fmaxf(v, __shfl_xor(v, o, 64));
  return v;
}
__device__ __forceinline__ float waveSum(float v) {
  #pragma unroll
  for (int o = 32; o >= 1; o >>= 1) v += __shfl_xor(v, o, 64);
  return v;
}

// Repack tokens: stories[b][t][l] (int32) -> tok16[(t*32+b)*16 + l] (u16).
__global__ __launch_bounds__(256) void tok_conv(const int* __restrict__ st,
                                                unsigned short* __restrict__ tok16) {
  int i = blockIdx.x * 256 + threadIdx.x;
  if (i >= BB * TT * LL) return;
  int l = i & 15;
  int tb = i >> 4;          // t*32 + b
  int b = tb & 31;
  int t = tb >> 5;
  tok16[i] = (unsigned short)st[b * (TT * LL) + t * LL + l];
}

// Transition softmax: Tn[n*8+k] = softmax(trans[n,:])[k], pad slot 7 = 0.
__global__ __launch_bounds__(256) void prep_trans(const float* __restrict__ tr,
                                                  float* __restrict__ Tn) {
  int n = blockIdx.x * 256 + threadIdx.x;
  if (n >= NST) return;
  float v[7];
  float m = -3.4e38f;
  #pragma unroll
  for (int k = 0; k < 7; ++k) { v[k] = tr[n * 7 + k]; m = fmaxf(m, v[k]); }
  float s = 0.f;
  #pragma unroll
  for (int k = 0; k < 7; ++k) { v[k] = fexp2((v[k] - m) * LOG2E); s += v[k]; }
  float inv = 1.0f / s;
  #pragma unroll
  for (int k = 0; k < 7; ++k) Tn[n * 8 + k] = v[k] * inv;
  Tn[n * 8 + 7] = 0.f;
}

// One workgroup per state n: stage row emis[n,0:V] (40KB) in LDS, compute
// row LSE from registers, then gather all T*B token sums.
// em layout: em[n][t][b] = em[n*2048 + t*32 + b]  (b fastest for coalescing
// in the recursion, which indexes threads as (n,b) with b in the low 5 bits).
__global__ __launch_bounds__(256) void emis_kernel(const float* __restrict__ emis,
                                                   const unsigned short* __restrict__ tok16,
                                                   float* __restrict__ em) {
  const int n = blockIdx.x;
  const int tid = threadIdx.x;
  __shared__ float row[VOC];
  __shared__ float sred[8];

  const float4* rp = (const float4*)(emis + (size_t)n * VOC);
  float4 regs[10];
  float lmax = -3.4e38f;
  #pragma unroll
  for (int it = 0; it < 10; ++it) {
    int i = tid + it * 256;
    if (i < VOC / 4) {
      float4 v = rp[i];
      regs[it] = v;
      ((float4*)row)[i] = v;
      lmax = fmaxf(lmax, fmaxf(fmaxf(v.x, v.y), fmaxf(v.z, v.w)));
    }
  }
  float wm = waveMax(lmax);
  if ((tid & 63) == 0) sred[tid >> 6] = wm;
  __syncthreads();  // also makes `row` visible to all
  float bm = fmaxf(fmaxf(sred[0], sred[1]), fmaxf(sred[2], sred[3]));

  float ls = 0.f;
  #pragma unroll
  for (int it = 0; it < 10; ++it) {
    int i = tid + it * 256;
    if (i < VOC / 4) {
      float4 v = regs[it];
      ls += fexp2((v.x - bm) * LOG2E);
      ls += fexp2((v.y - bm) * LOG2E);
      ls += fexp2((v.z - bm) * LOG2E);
      ls += fexp2((v.w - bm) * LOG2E);
    }
  }
  float wsum = waveSum(ls);
  if ((tid & 63) == 0) sred[4 + (tid >> 6)] = wsum;
  __syncthreads();
  float lse = bm + flog2(sred[4] + sred[5] + sred[6] + sred[7]) * LN2F;
  float sub = (float)LL * lse;

  // Gather: 2048 (t,b) pairs, 16 tokens each.
  for (int i = tid; i < TT * BB; i += 256) {
    const uint4* tp = (const uint4*)(tok16 + (size_t)i * 16);
    uint4 w0 = tp[0];
    uint4 w1 = tp[1];
    float s = row[w0.x & 0xFFFF] + row[w0.x >> 16]
            + row[w0.y & 0xFFFF] + row[w0.y >> 16]
            + row[w0.z & 0xFFFF] + row[w0.z >> 16]
            + row[w0.w & 0xFFFF] + row[w0.w >> 16]
            + row[w1.x & 0xFFFF] + row[w1.x >> 16]
            + row[w1.y & 0xFFFF] + row[w1.y >> 16]
            + row[w1.z & 0xFFFF] + row[w1.z >> 16]
            + row[w1.w & 0xFFFF] + row[w1.w >> 16];
    em[(size_t)n * (TT * BB) + i] = s - sub;
  }
}

// scores0[n][b] = em[n][0][b] + prior[n]   (prior unnormalized; global LSE
// shift is subtracted once in the final kernel).
__global__ __launch_bounds__(256) void init_kernel(const float* __restrict__ em,
                                                   const float* __restrict__ prior,
                                                   float* __restrict__ s0) {
  int idx = blockIdx.x * 256 + threadIdx.x;   // < NST*BB
  int n = idx >> 5, b = idx & 31;
  s0[idx] = em[((size_t)n << 11) + b] + prior[n];
}

// One forward step: new[n][b] = em_t[n][b] + m + ln(sum_k T[n][k]*exp(prev_k-m))
// prev_k = sp[(n - OFF[k]) & NMASK][b], OFF = {0,1,-1,32,-32,1024,2048}.
__global__ __launch_bounds__(256) void step_kernel(const float* __restrict__ sp,
                                                   float* __restrict__ sn,
                                                   const float* __restrict__ em_t,
                                                   const float* __restrict__ Tn) {
  int idx = blockIdx.x * 256 + threadIdx.x;   // < NST*BB
  int n = idx >> 5, b = idx & 31;
  float p0 = sp[idx];
  float p1 = sp[(((n - 1) & NMASK) << 5) | b];
  float p2 = sp[(((n + 1) & NMASK) << 5) | b];
  float p3 = sp[(((n - 32) & NMASK) << 5) | b];
  float p4 = sp[(((n + 32) & NMASK) << 5) | b];
  float p5 = sp[(((n - 1024) & NMASK) << 5) | b];
  float p6 = sp[(((n - 2048) & NMASK) << 5) | b];
  const float4* t4 = (const float4*)(Tn + ((size_t)n << 3));
  float4 ta = t4[0];
  float4 tb = t4[1];
  float m = fmaxf(p0, fmaxf(fmaxf(p1, p2), fmaxf(fmaxf(p3, p4), fmaxf(p5, p6))));
  float s = ta.x * fexp2((p0 - m) * LOG2E)
          + ta.y * fexp2((p1 - m) * LOG2E)
          + ta.z * fexp2((p2 - m) * LOG2E)
          + ta.w * fexp2((p3 - m) * LOG2E)
          + tb.x * fexp2((p4 - m) * LOG2E)
          + tb.y * fexp2((p5 - m) * LOG2E)
          + tb.z * fexp2((p6 - m) * LOG2E);
  sn[idx] = em_t[((size_t)n << 11) + b] + m + flog2(s) * LN2F;
}

// out[b] = LSE_n(scores[n][b]) - LSE_n(prior[n])
__global__ __launch_bounds__(256) void final_kernel(const float* __restrict__ sf,
                                                    const float* __restrict__ prior,
                                                    float* __restrict__ out) {
  int b = blockIdx.x;
  int tid = threadIdx.x;
  __shared__ float sred[8];

  float lmax = -3.4e38f;
  for (int n = tid; n < NST; n += 256) lmax = fmaxf(lmax, sf[(n << 5) + b]);
  float wm = waveMax(lmax);
  if ((tid & 63) == 0) sred[tid >> 6] = wm;
  __syncthreads();
  float bm = fmaxf(fmaxf(sred[0], sred[1]), fmaxf(sred[2], sred[3]));
  float ls = 0.f;
  for (int n = tid; n < NST; n += 256) ls += fexp2((sf[(n << 5) + b] - bm) * LOG2E);
  float wsum = waveSum(ls);
  if ((tid & 63) == 0) sred[4 + (tid >> 6)] = wsum;
  __syncthreads();
  float lse_s = bm + flog2(sred[4] + sred[5] + sred[6] + sred[7]) * LN2F;

  __syncthreads();
  float pmax = -3.4e38f;
  for (int n = tid; n < NST; n += 256) pmax = fmaxf(pmax, prior[n]);
  float wpm = waveMax(pmax);
  if ((tid & 63) == 0) sred[tid >> 6] = wpm;
  __syncthreads();
  float pm = fmaxf(fmaxf(sred[0], sred[1]), fmaxf(sred[2], sred[3]));
  float ps = 0.f;
  for (int n = tid; n < NST; n += 256) ps += fexp2((prior[n] - pm) * LOG2E);
  float wps = waveSum(ps);
  if ((tid & 63) == 0) sred[4 + (tid >> 6)] = wps;
  __syncthreads();
  float lse_p = pm + flog2(sred[4] + sred[5] + sred[6] + sred[7]) * LN2F;

  if (tid == 0) out[b] = lse_s - lse_p;
}

extern "C" void kernel_launch(void* const* d_in, const int* in_sizes, int n_in,
                              void* d_out, int out_size, void* d_ws, size_t ws_size,
                              hipStream_t stream) {
  const int* stories  = (const int*)d_in[0];
  const float* trans  = (const float*)d_in[3];
  const float* emis   = (const float*)d_in[4];
  const float* prior  = (const float*)d_in[5];
  float* out = (float*)d_out;

  char* ws = (char*)d_ws;
  float* em = (float*)ws;                                // NST*TT*BB f32 = 134.2 MB
  float* sA = (float*)(ws + (size_t)NST * TT * BB * 4);  // 2 MB
  float* sB = sA + (size_t)NST * BB;                     // 2 MB
  float* Tn = sB + (size_t)NST * BB;                     // NST*8 f32 = 512 KB
  unsigned short* tok16 = (unsigned short*)(Tn + (size_t)NST * 8);  // 64 KB

  tok_conv<<<(BB * TT * LL + 255) / 256, 256, 0, stream>>>(stories, tok16);
  prep_trans<<<(NST + 255) / 256, 256, 0, stream>>>(trans, Tn);
  emis_kernel<<<NST, 256, 0, stream>>>(emis, tok16, em);
  init_kernel<<<(NST * BB) / 256, 256, 0, stream>>>(em, prior, sA);

  float* cur = sA;
  float* nxt = sB;
  for (int t = 1; t < TT; ++t) {
    step_kernel<<<(NST * BB) / 256, 256, 0, stream>>>(cur, nxt, em + (size_t)t * BB, Tn);
    float* tmp = cur; cur = nxt; nxt = tmp;
  }
  final_kernel<<<BB, 256, 0, stream>>>(cur, prior, out);
}